// Round 2
// baseline (1208.001 us; speedup 1.0000x reference)
//
#include <hip/hip_runtime.h>
#include <hip/hip_bf16.h>

// DKVMN: B=128 S=1024 IN=256 M=64 D=128 OUT=128.
// Restructure: w_t = softmax(x @ (Wr K^T) + br K^T) is Mv-independent -> precompute.
// Scan is then an elementwise linear recurrence (parallel over b,d; serial in t).
// y = sigmoid(r@Wp+bp) deferred to a post-GEMM (r staged in d_out, overwritten).
//
// Round-2 hardening:
//  * runtime dtype probe (inputs may be bf16 OR fp32; harness labels ambiguous):
//    low-16-bits-of-word statistic on x decides; all kernels branch on a ws flag.
//  * time-chunked (4 x 256 steps) with Mv carried in ws fp32 -> total ws 25.2 MB
//    (was 101 MB), robust against a small ws_size.

#define B_   128
#define S_   1024
#define IN_  256
#define M_   64
#define D_   128
#define OUT_ 128
#define TC_  4
#define TL_  (S_ / TC_)   // 256 steps per chunk
#define RC_  (B_ * TL_)   // 32768 chunk-local rows

typedef __hip_bfloat16 bf16;
typedef unsigned int uint32;

__device__ __forceinline__ float tof(bf16 v) { return __bfloat162float(v); }
__device__ __forceinline__ bf16  tob(float v) { return __float2bfloat16(v); }
__device__ __forceinline__ float ldf(const float* p, long i) { return p[i]; }
__device__ __forceinline__ float ldf(const bf16* p, long i)  { return tof(p[i]); }
__device__ __forceinline__ void  stf(float* p, long i, float v) { p[i] = v; }
__device__ __forceinline__ void  stf(bf16* p, long i, float v)  { p[i] = tob(v); }
__device__ __forceinline__ void  unp(uint32 u, float& lo, float& hi) {
  lo = __uint_as_float(u << 16);
  hi = __uint_as_float(u & 0xFFFF0000u);
}

// ---------------- probe: decide fp32 (flag=1) vs bf16 (flag=0) inputs ----------------
__global__ __launch_bounds__(256) void k_probe(const uint32* __restrict__ xw,
                                               int* __restrict__ flag) {
  __shared__ int s[256];
  const int tid = threadIdx.x;
  int sc = 0;
#pragma unroll
  for (int k = 0; k < 8; ++k) {
    const uint32 u = xw[tid * 8 + k];
    const float v = __uint_as_float(u << 16);  // low 16 bits as bf16
    if (!(fabsf(v) < 4.0f)) sc++;              // catches big values AND NaN/Inf
  }
  s[tid] = sc;
  __syncthreads();
  for (int o = 128; o > 0; o >>= 1) {
    if (tid < o) s[tid] += s[tid + o];
    __syncthreads();
  }
  if (tid == 0) *flag = (s[0] > 64) ? 1 : 0;
}

// ---------------- K0: fold Wk = Wr @ K^T (256x64), bk = br @ K^T (64) ----------------
template <typename T>
__device__ void k0_body(const T* Wr, const T* br, const T* K,
                        float* Wk, float* bk) {
  const int idx = blockIdx.x * 256 + threadIdx.x;
  if (idx < IN_ * M_) {
    const int i = idx >> 6, m = idx & 63;
    float acc = 0.f;
    for (int d = 0; d < D_; ++d)
      acc = fmaf(ldf(Wr, (long)i * D_ + d), ldf(K, (long)m * D_ + d), acc);
    Wk[idx] = acc;  // idx == i*M_+m
  } else if (idx < IN_ * M_ + M_) {
    const int m = idx - IN_ * M_;
    float acc = 0.f;
    for (int d = 0; d < D_; ++d)
      acc = fmaf(ldf(br, d), ldf(K, (long)m * D_ + d), acc);
    bk[m] = acc;
  }
}

__global__ __launch_bounds__(256) void k0_fold(const void* Wr, const void* br,
                                               const void* K, float* Wk, float* bk,
                                               const int* flag) {
  if (*flag) k0_body<float>((const float*)Wr, (const float*)br, (const float*)K, Wk, bk);
  else       k0_body<bf16>((const bf16*)Wr, (const bf16*)br, (const bf16*)K, Wk, bk);
}

// ---------------- K1: fused v-GEMM (e=sigmoid, a=tanh) + scores + softmax ------------
// grid 1024: blk -> b = blk>>3, tb = blk&7 (32 rows each). 256 threads.
template <typename T>
__device__ void k1_body(const T* x, const T* Ww, const T* bw,
                        const float* Wk, const float* bk,
                        bf16* e_all, bf16* a_all, bf16* w_all,
                        int chunk, float* xs) {
  const int tid = threadIdx.x;
  const int b = blockIdx.x >> 3, tb = blockIdx.x & 7;
  const long lr0 = (long)b * TL_ + tb * 32;                 // chunk-local row base
  const long ar0 = (long)b * S_ + (long)chunk * TL_ + tb * 32;  // absolute row base
  const T* xg = x + ar0 * IN_;

  if constexpr (sizeof(T) == 4) {
#pragma unroll
    for (int k = 0; k < 32; ++k) {
      const int idx = k * 256 + tid;
      xs[idx] = ((const float*)xg)[idx];
    }
  } else {
    const uint32* xw = (const uint32*)xg;  // 4096 words
#pragma unroll
    for (int k = 0; k < 16; ++k) {
      const int j = k * 256 + tid;
      unp(xw[j], xs[2 * j], xs[2 * j + 1]);
    }
  }
  __syncthreads();

  // phase 1: v = x @ Ww + bw ; e = sigmoid(v), a = tanh(v)
  {
    const int c = tid & 127;
    const int rh = tid >> 7;  // 16 rows each
    float acc[16];
    const float bias = ldf(bw, c);
#pragma unroll
    for (int r = 0; r < 16; ++r) acc[r] = bias;
    for (int i = 0; i < IN_; i += 4) {
      float wv[4];
#pragma unroll
      for (int k = 0; k < 4; ++k) wv[k] = ldf(Ww, (long)(i + k) * D_ + c);
#pragma unroll
      for (int r = 0; r < 16; ++r) {
        const float4 xv = *(const float4*)&xs[(rh * 16 + r) * 256 + i];
        acc[r] = fmaf(xv.x, wv[0], acc[r]);
        acc[r] = fmaf(xv.y, wv[1], acc[r]);
        acc[r] = fmaf(xv.z, wv[2], acc[r]);
        acc[r] = fmaf(xv.w, wv[3], acc[r]);
      }
    }
#pragma unroll
    for (int r = 0; r < 16; ++r) {
      const float v = acc[r];
      const float sg = 1.0f / (1.0f + exp2f(-1.44269504f * v));
      const float ex2 = exp2f(2.88539008f * v);
      const float th = 1.0f - 2.0f / (ex2 + 1.0f);
      const long lr = lr0 + rh * 16 + r;
      e_all[lr * D_ + c] = tob(sg);
      a_all[lr * D_ + c] = tob(th);
    }
  }

  // phase 2: scores = x @ Wk + bk ; w = softmax over m=64 (one wave per 8 rows)
  {
    const int m = tid & 63;
    const int rq = tid >> 6;
    float acc[8];
    const float bias = bk[m];
#pragma unroll
    for (int r = 0; r < 8; ++r) acc[r] = bias;
    for (int i = 0; i < IN_; i += 4) {
      float wv[4];
#pragma unroll
      for (int k = 0; k < 4; ++k) wv[k] = Wk[(i + k) * M_ + m];
#pragma unroll
      for (int r = 0; r < 8; ++r) {
        const float4 xv = *(const float4*)&xs[(rq * 8 + r) * 256 + i];
        acc[r] = fmaf(xv.x, wv[0], acc[r]);
        acc[r] = fmaf(xv.y, wv[1], acc[r]);
        acc[r] = fmaf(xv.z, wv[2], acc[r]);
        acc[r] = fmaf(xv.w, wv[3], acc[r]);
      }
    }
#pragma unroll
    for (int r = 0; r < 8; ++r) {
      const float s = acc[r];
      float mx = s;
#pragma unroll
      for (int off = 32; off > 0; off >>= 1) mx = fmaxf(mx, __shfl_xor(mx, off, 64));
      const float ex = exp2f(1.44269504f * (s - mx));
      float sum = ex;
#pragma unroll
      for (int off = 32; off > 0; off >>= 1) sum += __shfl_xor(sum, off, 64);
      const long lr = lr0 + rq * 8 + r;
      w_all[lr * M_ + m] = tob(ex / sum);
    }
  }
}

__global__ __launch_bounds__(256) void k1_gemm(const void* x, const void* Ww,
                                               const void* bw, const float* Wk,
                                               const float* bk, bf16* e_all,
                                               bf16* a_all, bf16* w_all, int chunk,
                                               const int* flag) {
  __shared__ float xs[32 * 256];
  if (*flag) k1_body<float>((const float*)x, (const float*)Ww, (const float*)bw,
                            Wk, bk, e_all, a_all, w_all, chunk, xs);
  else       k1_body<bf16>((const bf16*)x, (const bf16*)Ww, (const bf16*)bw,
                           Wk, bk, e_all, a_all, w_all, chunk, xs);
}

// ---------------- K2: scan chunk. grid = B*4 x 64 threads. ---------------------------
// lane: mh = lane>>5 (which 32 m's), dl = lane&31; block: b = blk>>2, dq = blk&3.
template <typename T>
__device__ void k2_body(const T* Mv0, const bf16* e_all, const bf16* a_all,
                        const bf16* w_all, float* MvS, T* r_out, int chunk) {
  const int lane = threadIdx.x;
  const int mh = lane >> 5, dl = lane & 31;
  const int b = blockIdx.x >> 2, dq = blockIdx.x & 3;
  const int d = dq * 32 + dl;

  float Mv[32];
  if (chunk == 0) {
#pragma unroll
    for (int j = 0; j < 32; ++j)
      Mv[j] = ldf(Mv0, (long)(mh * 32 + j) * D_ + d);
  } else {
#pragma unroll
    for (int j = 0; j < 32; ++j)
      Mv[j] = MvS[((long)b * M_ + mh * 32 + j) * D_ + d];
  }

  const long lrbase = (long)b * TL_;
  const long arbase = (long)b * S_ + (long)chunk * TL_;
  for (int t = 0; t < TL_; ++t) {
    const long lr = lrbase + t;
    const float e = tof(e_all[lr * D_ + d]);
    const float a = tof(a_all[lr * D_ + d]);
    const uint4* wp = (const uint4*)(w_all + lr * M_ + mh * 32);  // 32 bf16 = 4 x uint4
    float wv[32];
#pragma unroll
    for (int q = 0; q < 4; ++q) {
      const uint4 u4 = wp[q];
      unp(u4.x, wv[q * 8 + 0], wv[q * 8 + 1]);
      unp(u4.y, wv[q * 8 + 2], wv[q * 8 + 3]);
      unp(u4.z, wv[q * 8 + 4], wv[q * 8 + 5]);
      unp(u4.w, wv[q * 8 + 6], wv[q * 8 + 7]);
    }
    float r = 0.f;
#pragma unroll
    for (int j = 0; j < 32; ++j) {
      r = fmaf(wv[j], Mv[j], r);                       // pre-update Mv
      Mv[j] = fmaf(wv[j], fmaf(-e, Mv[j], a), Mv[j]);  // Mv*(1-w e) + w a
    }
    r += __shfl_xor(r, 32, 64);
    if (mh == 0) stf(r_out, (arbase + t) * D_ + d, r);
  }
#pragma unroll
  for (int j = 0; j < 32; ++j)
    MvS[((long)b * M_ + mh * 32 + j) * D_ + d] = Mv[j];
}

__global__ __launch_bounds__(64) void k2_scan(const void* Mv0, const bf16* e_all,
                                              const bf16* a_all, const bf16* w_all,
                                              float* MvS, void* r_out, int chunk,
                                              const int* flag) {
  if (*flag) k2_body<float>((const float*)Mv0, e_all, a_all, w_all, MvS,
                            (float*)r_out, chunk);
  else       k2_body<bf16>((const bf16*)Mv0, e_all, a_all, w_all, MvS,
                           (bf16*)r_out, chunk);
}

// ---------------- K3: y = sigmoid(r @ Wp + bp), in place over d_out ------------------
template <typename T>
__device__ void k3_body(const T* Wp, const T* bp, T* io, float* rs) {
  const int tid = threadIdx.x;
  const long row0 = (long)blockIdx.x * 32;
#pragma unroll
  for (int k = 0; k < 16; ++k) {
    const int idx = k * 256 + tid;
    rs[idx] = ldf(io, row0 * D_ + idx);
  }
  __syncthreads();

  const int c = tid & 127;
  const int rh = tid >> 7;
  float acc[16];
  const float bias = ldf(bp, c);
#pragma unroll
  for (int r = 0; r < 16; ++r) acc[r] = bias;
  for (int i = 0; i < D_; i += 4) {
    float wv[4];
#pragma unroll
    for (int k = 0; k < 4; ++k) wv[k] = ldf(Wp, (long)(i + k) * OUT_ + c);
#pragma unroll
    for (int r = 0; r < 16; ++r) {
      const float4 xv = *(const float4*)&rs[(rh * 16 + r) * 128 + i];
      acc[r] = fmaf(xv.x, wv[0], acc[r]);
      acc[r] = fmaf(xv.y, wv[1], acc[r]);
      acc[r] = fmaf(xv.z, wv[2], acc[r]);
      acc[r] = fmaf(xv.w, wv[3], acc[r]);
    }
  }
#pragma unroll
  for (int r = 0; r < 16; ++r) {
    const float y = 1.0f / (1.0f + exp2f(-1.44269504f * acc[r]));
    stf(io, (row0 + rh * 16 + r) * OUT_ + c, y);
  }
}

__global__ __launch_bounds__(256) void k3_proj(const void* Wp, const void* bp,
                                               void* io, const int* flag) {
  __shared__ float rs[32 * 128];
  if (*flag) k3_body<float>((const float*)Wp, (const float*)bp, (float*)io, rs);
  else       k3_body<bf16>((const bf16*)Wp, (const bf16*)bp, (bf16*)io, rs);
}

extern "C" void kernel_launch(void* const* d_in, const int* in_sizes, int n_in,
                              void* d_out, int out_size, void* d_ws, size_t ws_size,
                              hipStream_t stream) {
  const void* x   = d_in[0];
  const void* mk  = d_in[1];
  const void* mv  = d_in[2];
  const void* Wr  = d_in[3];
  const void* br  = d_in[4];
  const void* Ww  = d_in[5];
  const void* bwv = d_in[6];
  const void* Wp  = d_in[7];
  const void* bp  = d_in[8];

  // ws layout (25.2 MB total):
  // [0,16)        int flag
  // [16,65552)    Wk fp32 256x64
  // [65552,65808) bk fp32 64
  // [65808, +8MB) e_all  bf16 32768x128 (chunk-local)
  // ( +8MB)       a_all  bf16 32768x128
  // ( +4MB)       w_all  bf16 32768x64
  // ( +4MB)       MvS    fp32 128x64x128
  char* ws = (char*)d_ws;
  int*   flag  = (int*)ws;
  float* Wk    = (float*)(ws + 16);
  float* bk    = (float*)(ws + 65552);
  bf16*  e_all = (bf16*)(ws + 65808);
  bf16*  a_all = e_all + (size_t)RC_ * D_;
  bf16*  w_all = a_all + (size_t)RC_ * D_;
  float* MvS   = (float*)(w_all + (size_t)RC_ * M_);

  k_probe<<<1, 256, 0, stream>>>((const uint32*)x, flag);
  k0_fold<<<(IN_ * M_ + M_ + 255) / 256, 256, 0, stream>>>(Wr, br, mk, Wk, bk, flag);
  for (int c = 0; c < TC_; ++c) {
    k1_gemm<<<RC_ / 32, 256, 0, stream>>>(x, Ww, bwv, Wk, bk, e_all, a_all, w_all,
                                          c, flag);
    k2_scan<<<B_ * 4, 64, 0, stream>>>(mv, e_all, a_all, w_all, MvS, d_out, c, flag);
  }
  k3_proj<<<(B_ * S_) / 32, 256, 0, stream>>>(Wp, bp, d_out, flag);
}

// Round 3
// 973.900 us; speedup vs baseline: 1.2404x; 1.2404x over previous
//
#include <hip/hip_runtime.h>
#include <hip/hip_bf16.h>

// DKVMN: B=128 S=1024 IN=256 M=64 D=128 OUT=128.
// w_t = softmax(x @ (Wr K^T) + br K^T) precomputed (Mv-independent); scan is an
// elementwise affine recurrence; y = sigmoid(r@Wp+bp) deferred to post-GEMM.
// R3: k2 at 8 waves/CU (lane = 8 m-groups x 8 d, 3-shfl reduce, prefetch);
//     k1 2 cols/thread (halved LDS b128 reads); e,a packed u32.

#define B_   128
#define S_   1024
#define IN_  256
#define M_   64
#define D_   128
#define OUT_ 128
#define TC_  4
#define TL_  (S_ / TC_)   // 256 steps per chunk
#define RC_  (B_ * TL_)   // 32768 chunk-local rows

typedef __hip_bfloat16 bf16;
typedef unsigned int uint32;

__device__ __forceinline__ float tof(bf16 v) { return __bfloat162float(v); }
__device__ __forceinline__ bf16  tob(float v) { return __float2bfloat16(v); }
__device__ __forceinline__ float ldf(const float* p, long i) { return p[i]; }
__device__ __forceinline__ float ldf(const bf16* p, long i)  { return tof(p[i]); }
__device__ __forceinline__ void  stf(float* p, long i, float v) { p[i] = v; }
__device__ __forceinline__ void  stf(bf16* p, long i, float v)  { p[i] = tob(v); }
__device__ __forceinline__ void  unp(uint32 u, float& lo, float& hi) {
  lo = __uint_as_float(u << 16);
  hi = __uint_as_float(u & 0xFFFF0000u);
}
__device__ __forceinline__ uint32 pk(float lo, float hi) {
  union { bf16 h; unsigned short u; } a, b;
  a.h = tob(lo); b.h = tob(hi);
  return (uint32)a.u | ((uint32)b.u << 16);
}

// ---------------- probe: decide fp32 (flag=1) vs bf16 (flag=0) inputs ----------------
__global__ __launch_bounds__(256) void k_probe(const uint32* __restrict__ xw,
                                               int* __restrict__ flag) {
  __shared__ int s[256];
  const int tid = threadIdx.x;
  int sc = 0;
#pragma unroll
  for (int k = 0; k < 8; ++k) {
    const uint32 u = xw[tid * 8 + k];
    const float v = __uint_as_float(u << 16);  // low 16 bits as bf16
    if (!(fabsf(v) < 4.0f)) sc++;              // catches big values AND NaN/Inf
  }
  s[tid] = sc;
  __syncthreads();
  for (int o = 128; o > 0; o >>= 1) {
    if (tid < o) s[tid] += s[tid + o];
    __syncthreads();
  }
  if (tid == 0) *flag = (s[0] > 64) ? 1 : 0;
}

// ---------------- K0: fold Wk = Wr @ K^T (256x64), bk = br @ K^T (64) ----------------
template <typename T>
__device__ void k0_body(const T* Wr, const T* br, const T* K,
                        float* Wk, float* bk) {
  const int idx = blockIdx.x * 256 + threadIdx.x;
  if (idx < IN_ * M_) {
    const int i = idx >> 6, m = idx & 63;
    float acc = 0.f;
    for (int d = 0; d < D_; ++d)
      acc = fmaf(ldf(Wr, (long)i * D_ + d), ldf(K, (long)m * D_ + d), acc);
    Wk[idx] = acc;  // idx == i*M_+m
  } else if (idx < IN_ * M_ + M_) {
    const int m = idx - IN_ * M_;
    float acc = 0.f;
    for (int d = 0; d < D_; ++d)
      acc = fmaf(ldf(br, d), ldf(K, (long)m * D_ + d), acc);
    bk[m] = acc;
  }
}

__global__ __launch_bounds__(256) void k0_fold(const void* Wr, const void* br,
                                               const void* K, float* Wk, float* bk,
                                               const int* flag) {
  if (*flag) k0_body<float>((const float*)Wr, (const float*)br, (const float*)K, Wk, bk);
  else       k0_body<bf16>((const bf16*)Wr, (const bf16*)br, (const bf16*)K, Wk, bk);
}

// ---------------- K1: fused v-GEMM (e=sigmoid, a=tanh) + scores + softmax ------------
// grid 1024: blk -> b = blk>>3, tb = blk&7 (32 rows each). 256 threads.
template <typename T>
__device__ void k1_body(const T* x, const T* Ww, const T* bw,
                        const float* Wk, const float* bk,
                        uint32* ea_all, bf16* w_all,
                        int chunk, float* xs) {
  const int tid = threadIdx.x;
  const int b = blockIdx.x >> 3, tb = blockIdx.x & 7;
  const long lr0 = (long)b * TL_ + tb * 32;                     // chunk-local row base
  const long ar0 = (long)b * S_ + (long)chunk * TL_ + tb * 32;  // absolute row base
  const T* xg = x + ar0 * IN_;

  if constexpr (sizeof(T) == 4) {
#pragma unroll
    for (int k = 0; k < 32; ++k) {
      const int idx = k * 256 + tid;
      xs[idx] = ((const float*)xg)[idx];
    }
  } else {
    const uint32* xw = (const uint32*)xg;  // 4096 words
#pragma unroll
    for (int k = 0; k < 16; ++k) {
      const int j = k * 256 + tid;
      unp(xw[j], xs[2 * j], xs[2 * j + 1]);
    }
  }
  __syncthreads();

  // phase 1: v = x @ Ww + bw ; e = sigmoid(v), a = tanh(v). 2 cols/thread.
  {
    const int c = tid & 63;   // cols c and c+64
    const int rg = tid >> 6;  // 4 groups of 8 rows
    float acc0[8], acc1[8];
    const float b0 = ldf(bw, c), b1 = ldf(bw, c + 64);
#pragma unroll
    for (int r = 0; r < 8; ++r) { acc0[r] = b0; acc1[r] = b1; }
    for (int i = 0; i < IN_; i += 4) {
      float w0[4], w1[4];
#pragma unroll
      for (int k = 0; k < 4; ++k) {
        w0[k] = ldf(Ww, (long)(i + k) * D_ + c);
        w1[k] = ldf(Ww, (long)(i + k) * D_ + c + 64);
      }
#pragma unroll
      for (int r = 0; r < 8; ++r) {
        const float4 xv = *(const float4*)&xs[(rg * 8 + r) * 256 + i];
        acc0[r] = fmaf(xv.x, w0[0], acc0[r]);
        acc0[r] = fmaf(xv.y, w0[1], acc0[r]);
        acc0[r] = fmaf(xv.z, w0[2], acc0[r]);
        acc0[r] = fmaf(xv.w, w0[3], acc0[r]);
        acc1[r] = fmaf(xv.x, w1[0], acc1[r]);
        acc1[r] = fmaf(xv.y, w1[1], acc1[r]);
        acc1[r] = fmaf(xv.z, w1[2], acc1[r]);
        acc1[r] = fmaf(xv.w, w1[3], acc1[r]);
      }
    }
#pragma unroll
    for (int r = 0; r < 8; ++r) {
      const long lr = lr0 + rg * 8 + r;
      {
        const float v = acc0[r];
        const float sg = 1.0f / (1.0f + exp2f(-1.44269504f * v));
        const float th = 1.0f - 2.0f / (exp2f(2.88539008f * v) + 1.0f);
        ea_all[lr * D_ + c] = pk(sg, th);
      }
      {
        const float v = acc1[r];
        const float sg = 1.0f / (1.0f + exp2f(-1.44269504f * v));
        const float th = 1.0f - 2.0f / (exp2f(2.88539008f * v) + 1.0f);
        ea_all[lr * D_ + c + 64] = pk(sg, th);
      }
    }
  }

  // phase 2: scores = x @ Wk + bk ; softmax over m=64. 2 m-cols/thread,
  // 32-lane-group shfl reduction (lanes of a group hold one row's 64 m's in 2 regs).
  {
    const int m = tid & 31;   // m and m+32
    const int rg = tid >> 5;  // 8 groups of 4 rows
    float a0[4], a1[4];
    const float b0 = bk[m], b1 = bk[m + 32];
#pragma unroll
    for (int r = 0; r < 4; ++r) { a0[r] = b0; a1[r] = b1; }
    for (int i = 0; i < IN_; i += 4) {
      float w0[4], w1[4];
#pragma unroll
      for (int k = 0; k < 4; ++k) {
        w0[k] = Wk[(i + k) * M_ + m];
        w1[k] = Wk[(i + k) * M_ + m + 32];
      }
#pragma unroll
      for (int r = 0; r < 4; ++r) {
        const float4 xv = *(const float4*)&xs[(rg * 4 + r) * 256 + i];
        a0[r] = fmaf(xv.x, w0[0], a0[r]);
        a0[r] = fmaf(xv.y, w0[1], a0[r]);
        a0[r] = fmaf(xv.z, w0[2], a0[r]);
        a0[r] = fmaf(xv.w, w0[3], a0[r]);
        a1[r] = fmaf(xv.x, w1[0], a1[r]);
        a1[r] = fmaf(xv.y, w1[1], a1[r]);
        a1[r] = fmaf(xv.z, w1[2], a1[r]);
        a1[r] = fmaf(xv.w, w1[3], a1[r]);
      }
    }
#pragma unroll
    for (int r = 0; r < 4; ++r) {
      float mx = fmaxf(a0[r], a1[r]);
#pragma unroll
      for (int off = 16; off > 0; off >>= 1) mx = fmaxf(mx, __shfl_xor(mx, off, 64));
      const float e0 = exp2f(1.44269504f * (a0[r] - mx));
      const float e1 = exp2f(1.44269504f * (a1[r] - mx));
      float sum = e0 + e1;
#pragma unroll
      for (int off = 16; off > 0; off >>= 1) sum += __shfl_xor(sum, off, 64);
      const float inv = 1.0f / sum;
      const long lr = lr0 + rg * 4 + r;
      w_all[lr * M_ + m]      = tob(e0 * inv);
      w_all[lr * M_ + m + 32] = tob(e1 * inv);
    }
  }
}

__global__ __launch_bounds__(256) void k1_gemm(const void* x, const void* Ww,
                                               const void* bw, const float* Wk,
                                               const float* bk, uint32* ea_all,
                                               bf16* w_all, int chunk,
                                               const int* flag) {
  __shared__ float xs[32 * 256];
  if (*flag) k1_body<float>((const float*)x, (const float*)Ww, (const float*)bw,
                            Wk, bk, ea_all, w_all, chunk, xs);
  else       k1_body<bf16>((const bf16*)x, (const bf16*)Ww, (const bf16*)bw,
                           Wk, bk, ea_all, w_all, chunk, xs);
}

// ---------------- K2: scan chunk. grid = B*16 x 64 threads (1 wave). -----------------
// lane = mg*8 + dl: mg in [0,8) owns m = mg*8..+8 (8 Mv regs); d = dg*8 + dl.
// r-reduction across mg = shfl_xor 8/16/32. Next-step loads prefetched.
template <typename T>
__device__ void k2_body(const T* Mv0, const uint32* ea_all, const bf16* w_all,
                        float* MvS, T* r_out, int chunk) {
  const int lane = threadIdx.x;
  const int mg = lane >> 3, dl = lane & 7;
  const int b = blockIdx.x >> 4, dg = blockIdx.x & 15;
  const int d = dg * 8 + dl;
  const int m0 = mg * 8;

  float Mv[8];
  if (chunk == 0) {
#pragma unroll
    for (int j = 0; j < 8; ++j)
      Mv[j] = ldf(Mv0, (long)(m0 + j) * D_ + d);
  } else {
#pragma unroll
    for (int j = 0; j < 8; ++j)
      Mv[j] = MvS[((long)b * M_ + m0 + j) * D_ + d];
  }

  const long lrbase = (long)b * TL_;
  const long arbase = (long)b * S_ + (long)chunk * TL_;

  uint32 ea = ea_all[lrbase * D_ + d];
  uint4 w4 = *(const uint4*)(w_all + lrbase * M_ + m0);

  for (int t = 0; t < TL_; ++t) {
    // prefetch t+1 (clamped; issues before this step's compute)
    const long lrn = lrbase + (t + 1 < TL_ ? t + 1 : TL_ - 1);
    const uint32 ean = ea_all[lrn * D_ + d];
    const uint4 w4n = *(const uint4*)(w_all + lrn * M_ + m0);

    float e, a;
    unp(ea, e, a);
    float wv[8];
    unp(w4.x, wv[0], wv[1]);
    unp(w4.y, wv[2], wv[3]);
    unp(w4.z, wv[4], wv[5]);
    unp(w4.w, wv[6], wv[7]);

    float r = 0.f;
#pragma unroll
    for (int j = 0; j < 8; ++j) {
      r = fmaf(wv[j], Mv[j], r);                       // pre-update Mv
      Mv[j] = fmaf(wv[j], fmaf(-e, Mv[j], a), Mv[j]);  // Mv*(1-w e) + w a
    }
    r += __shfl_xor(r, 8, 64);
    r += __shfl_xor(r, 16, 64);
    r += __shfl_xor(r, 32, 64);
    if (mg == 0) stf(r_out, (arbase + t) * D_ + d, r);

    ea = ean;
    w4 = w4n;
  }
#pragma unroll
  for (int j = 0; j < 8; ++j)
    MvS[((long)b * M_ + m0 + j) * D_ + d] = Mv[j];
}

__global__ __launch_bounds__(64) void k2_scan(const void* Mv0, const uint32* ea_all,
                                              const bf16* w_all, float* MvS,
                                              void* r_out, int chunk,
                                              const int* flag) {
  if (*flag) k2_body<float>((const float*)Mv0, ea_all, w_all, MvS,
                            (float*)r_out, chunk);
  else       k2_body<bf16>((const bf16*)Mv0, ea_all, w_all, MvS,
                           (bf16*)r_out, chunk);
}

// ---------------- K3: y = sigmoid(r @ Wp + bp), in place over d_out ------------------
template <typename T>
__device__ void k3_body(const T* Wp, const T* bp, T* io, float* rs) {
  const int tid = threadIdx.x;
  const long row0 = (long)blockIdx.x * 32;
#pragma unroll
  for (int k = 0; k < 16; ++k) {
    const int idx = k * 256 + tid;
    rs[idx] = ldf(io, row0 * D_ + idx);
  }
  __syncthreads();

  const int c = tid & 63;   // cols c, c+64
  const int rg = tid >> 6;  // 4 groups of 8 rows
  float acc0[8], acc1[8];
  const float b0 = ldf(bp, c), b1 = ldf(bp, c + 64);
#pragma unroll
  for (int r = 0; r < 8; ++r) { acc0[r] = b0; acc1[r] = b1; }
  for (int i = 0; i < D_; i += 4) {
    float w0[4], w1[4];
#pragma unroll
    for (int k = 0; k < 4; ++k) {
      w0[k] = ldf(Wp, (long)(i + k) * OUT_ + c);
      w1[k] = ldf(Wp, (long)(i + k) * OUT_ + c + 64);
    }
#pragma unroll
    for (int r = 0; r < 8; ++r) {
      const float4 xv = *(const float4*)&rs[(rg * 8 + r) * 128 + i];
      acc0[r] = fmaf(xv.x, w0[0], acc0[r]);
      acc0[r] = fmaf(xv.y, w0[1], acc0[r]);
      acc0[r] = fmaf(xv.z, w0[2], acc0[r]);
      acc0[r] = fmaf(xv.w, w0[3], acc0[r]);
      acc1[r] = fmaf(xv.x, w1[0], acc1[r]);
      acc1[r] = fmaf(xv.y, w1[1], acc1[r]);
      acc1[r] = fmaf(xv.z, w1[2], acc1[r]);
      acc1[r] = fmaf(xv.w, w1[3], acc1[r]);
    }
  }
#pragma unroll
  for (int r = 0; r < 8; ++r) {
    const long row = row0 + rg * 8 + r;
    stf(io, row * OUT_ + c,      1.0f / (1.0f + exp2f(-1.44269504f * acc0[r])));
    stf(io, row * OUT_ + c + 64, 1.0f / (1.0f + exp2f(-1.44269504f * acc1[r])));
  }
}

__global__ __launch_bounds__(256) void k3_proj(const void* Wp, const void* bp,
                                               void* io, const int* flag) {
  __shared__ float rs[32 * 128];
  if (*flag) k3_body<float>((const float*)Wp, (const float*)bp, (float*)io, rs);
  else       k3_body<bf16>((const bf16*)Wp, (const bf16*)bp, (bf16*)io, rs);
}

extern "C" void kernel_launch(void* const* d_in, const int* in_sizes, int n_in,
                              void* d_out, int out_size, void* d_ws, size_t ws_size,
                              hipStream_t stream) {
  const void* x   = d_in[0];
  const void* mk  = d_in[1];
  const void* mv  = d_in[2];
  const void* Wr  = d_in[3];
  const void* br  = d_in[4];
  const void* Ww  = d_in[5];
  const void* bwv = d_in[6];
  const void* Wp  = d_in[7];
  const void* bp  = d_in[8];

  // ws layout (~24.3 MB): flag | Wk fp32 64KB | bk | ea u32 16MB | w bf16 4MB | MvS fp32 4MB
  char* ws = (char*)d_ws;
  int*    flag  = (int*)ws;
  float*  Wk    = (float*)(ws + 16);
  float*  bk    = (float*)(ws + 65552);
  uint32* ea_all = (uint32*)(ws + 65808);
  bf16*   w_all = (bf16*)(ea_all + (size_t)RC_ * D_);
  float*  MvS   = (float*)(w_all + (size_t)RC_ * M_);

  k_probe<<<1, 256, 0, stream>>>((const uint32*)x, flag);
  k0_fold<<<(IN_ * M_ + M_ + 255) / 256, 256, 0, stream>>>(Wr, br, mk, Wk, bk, flag);
  for (int c = 0; c < TC_; ++c) {
    k1_gemm<<<RC_ / 32, 256, 0, stream>>>(x, Ww, bwv, Wk, bk, ea_all, w_all, c, flag);
    k2_scan<<<B_ * 16, 64, 0, stream>>>(mv, ea_all, w_all, MvS, d_out, c, flag);
  }
  k3_proj<<<(B_ * S_) / 32, 256, 0, stream>>>(Wp, bp, d_out, flag);
}

// Round 4
// 858.949 us; speedup vs baseline: 1.4064x; 1.1338x over previous
//
#include <hip/hip_runtime.h>
#include <hip/hip_bf16.h>

// DKVMN: B=128 S=1024 IN=256 M=64 D=128 OUT=128.
// w_t = softmax(x @ (Wr K^T) + br K^T) precomputed (Mv-independent); scan is an
// elementwise affine recurrence; y = sigmoid(r@Wp+bp) deferred to post-GEMM.
// R4: k2 16 waves/CU (mg16 x dl4), prefetch ring depth 4, XCD swizzle (same-b
//     blocks share an XCD so w_all is L2-shared); k1/k3 4 cols/thread (LDS
//     b128 reads halved; each float4 feeds 16 FMAs).

#define B_   128
#define S_   1024
#define IN_  256
#define M_   64
#define D_   128
#define OUT_ 128
#define TC_  4
#define TL_  (S_ / TC_)   // 256 steps per chunk
#define RC_  (B_ * TL_)   // 32768 chunk-local rows

typedef __hip_bfloat16 bf16;
typedef unsigned int uint32;

__device__ __forceinline__ float tof(bf16 v) { return __bfloat162float(v); }
__device__ __forceinline__ bf16  tob(float v) { return __float2bfloat16(v); }
__device__ __forceinline__ float ldf(const float* p, long i) { return p[i]; }
__device__ __forceinline__ float ldf(const bf16* p, long i)  { return tof(p[i]); }
__device__ __forceinline__ void  stf(float* p, long i, float v) { p[i] = v; }
__device__ __forceinline__ void  stf(bf16* p, long i, float v)  { p[i] = tob(v); }
__device__ __forceinline__ void  unp(uint32 u, float& lo, float& hi) {
  lo = __uint_as_float(u << 16);
  hi = __uint_as_float(u & 0xFFFF0000u);
}
__device__ __forceinline__ uint32 pk(float lo, float hi) {
  union { bf16 h; unsigned short u; } a, b;
  a.h = tob(lo); b.h = tob(hi);
  return (uint32)a.u | ((uint32)b.u << 16);
}

// ---------------- probe: decide fp32 (flag=1) vs bf16 (flag=0) inputs ----------------
__global__ __launch_bounds__(256) void k_probe(const uint32* __restrict__ xw,
                                               int* __restrict__ flag) {
  __shared__ int s[256];
  const int tid = threadIdx.x;
  int sc = 0;
#pragma unroll
  for (int k = 0; k < 8; ++k) {
    const uint32 u = xw[tid * 8 + k];
    const float v = __uint_as_float(u << 16);  // low 16 bits as bf16
    if (!(fabsf(v) < 4.0f)) sc++;              // catches big values AND NaN/Inf
  }
  s[tid] = sc;
  __syncthreads();
  for (int o = 128; o > 0; o >>= 1) {
    if (tid < o) s[tid] += s[tid + o];
    __syncthreads();
  }
  if (tid == 0) *flag = (s[0] > 64) ? 1 : 0;
}

// ---------------- K0: fold Wk = Wr @ K^T (256x64), bk = br @ K^T (64) ----------------
template <typename T>
__device__ void k0_body(const T* Wr, const T* br, const T* K,
                        float* Wk, float* bk) {
  const int idx = blockIdx.x * 256 + threadIdx.x;
  if (idx < IN_ * M_) {
    const int i = idx >> 6, m = idx & 63;
    float acc = 0.f;
    for (int d = 0; d < D_; ++d)
      acc = fmaf(ldf(Wr, (long)i * D_ + d), ldf(K, (long)m * D_ + d), acc);
    Wk[idx] = acc;  // idx == i*M_+m
  } else if (idx < IN_ * M_ + M_) {
    const int m = idx - IN_ * M_;
    float acc = 0.f;
    for (int d = 0; d < D_; ++d)
      acc = fmaf(ldf(br, d), ldf(K, (long)m * D_ + d), acc);
    bk[m] = acc;
  }
}

__global__ __launch_bounds__(256) void k0_fold(const void* Wr, const void* br,
                                               const void* K, float* Wk, float* bk,
                                               const int* flag) {
  if (*flag) k0_body<float>((const float*)Wr, (const float*)br, (const float*)K, Wk, bk);
  else       k0_body<bf16>((const bf16*)Wr, (const bf16*)br, (const bf16*)K, Wk, bk);
}

// ---------------- K1: fused v-GEMM (e=sigmoid, a=tanh) + scores + softmax ------------
// grid 1024: blk -> b = blk>>3, tb = blk&7 (32 rows each). 256 threads.
template <typename T>
__device__ void k1_body(const T* x, const T* Ww, const T* bw,
                        const float* Wk, const float* bk,
                        uint32* ea_all, bf16* w_all,
                        int chunk, float* xs) {
  const int tid = threadIdx.x;
  const int b = blockIdx.x >> 3, tb = blockIdx.x & 7;
  const long lr0 = (long)b * TL_ + tb * 32;                     // chunk-local row base
  const long ar0 = (long)b * S_ + (long)chunk * TL_ + tb * 32;  // absolute row base
  const T* xg = x + ar0 * IN_;

  if constexpr (sizeof(T) == 4) {
#pragma unroll
    for (int k = 0; k < 32; ++k) {
      const int idx = k * 256 + tid;
      xs[idx] = ((const float*)xg)[idx];
    }
  } else {
    const uint32* xw = (const uint32*)xg;  // 4096 words
#pragma unroll
    for (int k = 0; k < 16; ++k) {
      const int j = k * 256 + tid;
      unp(xw[j], xs[2 * j], xs[2 * j + 1]);
    }
  }
  __syncthreads();

  // phase 1: v = x @ Ww + bw ; e = sigmoid(v), a = tanh(v). 4 cols x 4 rows / thread.
  {
    const int c = tid & 31;   // cols c + 32*g
    const int rg = tid >> 5;  // 8 groups of 4 rows
    float acc[4][4];
#pragma unroll
    for (int g = 0; g < 4; ++g) {
      const float bb = ldf(bw, c + 32 * g);
#pragma unroll
      for (int r = 0; r < 4; ++r) acc[r][g] = bb;
    }
    for (int i = 0; i < IN_; i += 4) {
      float w[4][4];
#pragma unroll
      for (int k = 0; k < 4; ++k)
#pragma unroll
        for (int g = 0; g < 4; ++g)
          w[k][g] = ldf(Ww, (long)(i + k) * D_ + c + 32 * g);
#pragma unroll
      for (int r = 0; r < 4; ++r) {
        const float4 xv = *(const float4*)&xs[(rg * 4 + r) * 256 + i];
#pragma unroll
        for (int g = 0; g < 4; ++g) {
          acc[r][g] = fmaf(xv.x, w[0][g], acc[r][g]);
          acc[r][g] = fmaf(xv.y, w[1][g], acc[r][g]);
          acc[r][g] = fmaf(xv.z, w[2][g], acc[r][g]);
          acc[r][g] = fmaf(xv.w, w[3][g], acc[r][g]);
        }
      }
    }
#pragma unroll
    for (int r = 0; r < 4; ++r) {
      const long lr = lr0 + rg * 4 + r;
#pragma unroll
      for (int g = 0; g < 4; ++g) {
        const float v = acc[r][g];
        const float sg = 1.0f / (1.0f + exp2f(-1.44269504f * v));
        const float th = 1.0f - 2.0f / (exp2f(2.88539008f * v) + 1.0f);
        ea_all[lr * D_ + c + 32 * g] = pk(sg, th);
      }
    }
  }

  // phase 2: scores = x @ Wk + bk ; softmax over m=64. 4 m-cols x 2 rows / thread.
  // 16-lane groups (same rg) hold one row's 64 m's in 4 regs.
  {
    const int m = tid & 15;   // m + 16*g
    const int rg = tid >> 4;  // 16 groups of 2 rows
    float acc[2][4];
#pragma unroll
    for (int g = 0; g < 4; ++g) {
      const float bb = bk[m + 16 * g];
#pragma unroll
      for (int r = 0; r < 2; ++r) acc[r][g] = bb;
    }
    for (int i = 0; i < IN_; i += 4) {
      float w[4][4];
#pragma unroll
      for (int k = 0; k < 4; ++k)
#pragma unroll
        for (int g = 0; g < 4; ++g)
          w[k][g] = Wk[(i + k) * M_ + m + 16 * g];
#pragma unroll
      for (int r = 0; r < 2; ++r) {
        const float4 xv = *(const float4*)&xs[(rg * 2 + r) * 256 + i];
#pragma unroll
        for (int g = 0; g < 4; ++g) {
          acc[r][g] = fmaf(xv.x, w[0][g], acc[r][g]);
          acc[r][g] = fmaf(xv.y, w[1][g], acc[r][g]);
          acc[r][g] = fmaf(xv.z, w[2][g], acc[r][g]);
          acc[r][g] = fmaf(xv.w, w[3][g], acc[r][g]);
        }
      }
    }
#pragma unroll
    for (int r = 0; r < 2; ++r) {
      float mx = fmaxf(fmaxf(acc[r][0], acc[r][1]), fmaxf(acc[r][2], acc[r][3]));
#pragma unroll
      for (int off = 8; off > 0; off >>= 1) mx = fmaxf(mx, __shfl_xor(mx, off, 64));
      float ex[4], sum = 0.f;
#pragma unroll
      for (int g = 0; g < 4; ++g) {
        ex[g] = exp2f(1.44269504f * (acc[r][g] - mx));
        sum += ex[g];
      }
#pragma unroll
      for (int off = 8; off > 0; off >>= 1) sum += __shfl_xor(sum, off, 64);
      const float inv = 1.0f / sum;
      const long lr = lr0 + rg * 2 + r;
#pragma unroll
      for (int g = 0; g < 4; ++g)
        w_all[lr * M_ + m + 16 * g] = tob(ex[g] * inv);
    }
  }
}

__global__ __launch_bounds__(256) void k1_gemm(const void* x, const void* Ww,
                                               const void* bw, const float* Wk,
                                               const float* bk, uint32* ea_all,
                                               bf16* w_all, int chunk,
                                               const int* flag) {
  __shared__ float xs[32 * 256];
  if (*flag) k1_body<float>((const float*)x, (const float*)Ww, (const float*)bw,
                            Wk, bk, ea_all, w_all, chunk, xs);
  else       k1_body<bf16>((const bf16*)x, (const bf16*)Ww, (const bf16*)bw,
                           Wk, bk, ea_all, w_all, chunk, xs);
}

// ---------------- K2: scan chunk. grid = B*32 (swizzled) x 64 threads. ---------------
// blk = dg*128 + b  (all 32 same-b blocks share blk%8 -> same XCD -> w_all L2-shared).
// lane = mg*4 + dl: mg in [0,16) owns m = mg*4..+4; d = dg*4 + dl.
// Prefetch ring depth 4. r-reduction = shfl_xor 4/8/16/32.
template <typename T>
__device__ void k2_body(const T* Mv0, const uint32* ea_all, const bf16* w_all,
                        float* MvS, T* r_out, int chunk) {
  const int lane = threadIdx.x;
  const int mg = lane >> 2, dl = lane & 3;
  const int b = blockIdx.x & 127, dg = blockIdx.x >> 7;
  const int d = dg * 4 + dl;
  const int m0 = mg * 4;

  float Mv[4];
  if (chunk == 0) {
#pragma unroll
    for (int j = 0; j < 4; ++j)
      Mv[j] = ldf(Mv0, (long)(m0 + j) * D_ + d);
  } else {
#pragma unroll
    for (int j = 0; j < 4; ++j)
      Mv[j] = MvS[((long)b * M_ + m0 + j) * D_ + d];
  }

  const long lrbase = (long)b * TL_;
  const long arbase = (long)b * S_ + (long)chunk * TL_;

  uint32 er[4];
  uint2  wr[4];
#pragma unroll
  for (int p = 0; p < 4; ++p) {
    er[p] = ea_all[(lrbase + p) * D_ + d];
    wr[p] = *(const uint2*)(w_all + (lrbase + p) * M_ + m0);
  }

  for (int t = 0; t < TL_; t += 4) {
#pragma unroll
    for (int p = 0; p < 4; ++p) {
      const int tt = t + p;
      float e, a;
      unp(er[p], e, a);
      float wv[4];
      unp(wr[p].x, wv[0], wv[1]);
      unp(wr[p].y, wv[2], wv[3]);
      // refill slot p with step tt+4 (clamped) — 4-step latency cover
      const long lrn = lrbase + (tt + 4 < TL_ ? tt + 4 : TL_ - 1);
      er[p] = ea_all[lrn * D_ + d];
      wr[p] = *(const uint2*)(w_all + lrn * M_ + m0);

      float r = 0.f;
#pragma unroll
      for (int j = 0; j < 4; ++j) {
        r = fmaf(wv[j], Mv[j], r);                       // pre-update Mv
        Mv[j] = fmaf(wv[j], fmaf(-e, Mv[j], a), Mv[j]);  // Mv*(1-w e) + w a
      }
      r += __shfl_xor(r, 4, 64);
      r += __shfl_xor(r, 8, 64);
      r += __shfl_xor(r, 16, 64);
      r += __shfl_xor(r, 32, 64);
      if (mg == 0) stf(r_out, (arbase + tt) * D_ + d, r);
    }
  }
#pragma unroll
  for (int j = 0; j < 4; ++j)
    MvS[((long)b * M_ + m0 + j) * D_ + d] = Mv[j];
}

__global__ __launch_bounds__(64) void k2_scan(const void* Mv0, const uint32* ea_all,
                                              const bf16* w_all, float* MvS,
                                              void* r_out, int chunk,
                                              const int* flag) {
  if (*flag) k2_body<float>((const float*)Mv0, ea_all, w_all, MvS,
                            (float*)r_out, chunk);
  else       k2_body<bf16>((const bf16*)Mv0, ea_all, w_all, MvS,
                           (bf16*)r_out, chunk);
}

// ---------------- K3: y = sigmoid(r @ Wp + bp), in place over d_out ------------------
template <typename T>
__device__ void k3_body(const T* Wp, const T* bp, T* io, float* rs) {
  const int tid = threadIdx.x;
  const long row0 = (long)blockIdx.x * 32;
#pragma unroll
  for (int k = 0; k < 16; ++k) {
    const int idx = k * 256 + tid;
    rs[idx] = ldf(io, row0 * D_ + idx);
  }
  __syncthreads();

  const int c = tid & 31;   // cols c + 32*g
  const int rg = tid >> 5;  // 8 groups of 4 rows
  float acc[4][4];
#pragma unroll
  for (int g = 0; g < 4; ++g) {
    const float bb = ldf(bp, c + 32 * g);
#pragma unroll
    for (int r = 0; r < 4; ++r) acc[r][g] = bb;
  }
  for (int i = 0; i < D_; i += 4) {
    float w[4][4];
#pragma unroll
    for (int k = 0; k < 4; ++k)
#pragma unroll
      for (int g = 0; g < 4; ++g)
        w[k][g] = ldf(Wp, (long)(i + k) * OUT_ + c + 32 * g);
#pragma unroll
    for (int r = 0; r < 4; ++r) {
      const float4 xv = *(const float4*)&rs[(rg * 4 + r) * 128 + i];
#pragma unroll
      for (int g = 0; g < 4; ++g) {
        acc[r][g] = fmaf(xv.x, w[0][g], acc[r][g]);
        acc[r][g] = fmaf(xv.y, w[1][g], acc[r][g]);
        acc[r][g] = fmaf(xv.z, w[2][g], acc[r][g]);
        acc[r][g] = fmaf(xv.w, w[3][g], acc[r][g]);
      }
    }
  }
#pragma unroll
  for (int r = 0; r < 4; ++r) {
    const long row = row0 + rg * 4 + r;
#pragma unroll
    for (int g = 0; g < 4; ++g)
      stf(io, row * OUT_ + c + 32 * g,
          1.0f / (1.0f + exp2f(-1.44269504f * acc[r][g])));
  }
}

__global__ __launch_bounds__(256) void k3_proj(const void* Wp, const void* bp,
                                               void* io, const int* flag) {
  __shared__ float rs[32 * 128];
  if (*flag) k3_body<float>((const float*)Wp, (const float*)bp, (float*)io, rs);
  else       k3_body<bf16>((const bf16*)Wp, (const bf16*)bp, (bf16*)io, rs);
}

extern "C" void kernel_launch(void* const* d_in, const int* in_sizes, int n_in,
                              void* d_out, int out_size, void* d_ws, size_t ws_size,
                              hipStream_t stream) {
  const void* x   = d_in[0];
  const void* mk  = d_in[1];
  const void* mv  = d_in[2];
  const void* Wr  = d_in[3];
  const void* br  = d_in[4];
  const void* Ww  = d_in[5];
  const void* bwv = d_in[6];
  const void* Wp  = d_in[7];
  const void* bp  = d_in[8];

  // ws layout (~24.3 MB): flag | Wk fp32 64KB | bk | ea u32 16MB | w bf16 4MB | MvS fp32 4MB
  char* ws = (char*)d_ws;
  int*    flag   = (int*)ws;
  float*  Wk     = (float*)(ws + 16);
  float*  bk     = (float*)(ws + 65552);
  uint32* ea_all = (uint32*)(ws + 65808);
  bf16*   w_all  = (bf16*)(ea_all + (size_t)RC_ * D_);
  float*  MvS    = (float*)(w_all + (size_t)RC_ * M_);

  k_probe<<<1, 256, 0, stream>>>((const uint32*)x, flag);
  k0_fold<<<(IN_ * M_ + M_ + 255) / 256, 256, 0, stream>>>(Wr, br, mk, Wk, bk, flag);
  for (int c = 0; c < TC_; ++c) {
    k1_gemm<<<RC_ / 32, 256, 0, stream>>>(x, Ww, bwv, Wk, bk, ea_all, w_all, c, flag);
    k2_scan<<<B_ * 32, 64, 0, stream>>>(mv, ea_all, w_all, MvS, d_out, c, flag);
  }
  k3_proj<<<(B_ * S_) / 32, 256, 0, stream>>>(Wp, bp, d_out, flag);
}

// Round 5
// 825.109 us; speedup vs baseline: 1.4640x; 1.0410x over previous
//
#include <hip/hip_runtime.h>
#include <hip/hip_bf16.h>

// DKVMN: B=128 S=1024 IN=256 M=64 D=128 OUT=128.
// w_t = softmax(x @ (Wr K^T) + br K^T) precomputed (Mv-independent); scan is an
// elementwise affine recurrence; y = sigmoid(r@Wp+bp) deferred to post-GEMM.
// R5: k1/k3 as bf16 MFMA GEMMs (16x16x32, no LDS, pre-transposed W); k2 with
//     batch-8 register ping-pong prefetch; fp32 VALU fallbacks kept (flag).

#define B_   128
#define S_   1024
#define IN_  256
#define M_   64
#define D_   128
#define OUT_ 128
#define TC_  4
#define TL_  (S_ / TC_)   // 256 steps per chunk
#define RC_  (B_ * TL_)   // 32768 chunk-local rows

typedef __hip_bfloat16 bf16;
typedef unsigned int uint32;
typedef __attribute__((ext_vector_type(8))) short s16x8;
typedef __attribute__((ext_vector_type(4))) float f32x4;

__device__ __forceinline__ float tof(bf16 v) { return __bfloat162float(v); }
__device__ __forceinline__ bf16  tob(float v) { return __float2bfloat16(v); }
__device__ __forceinline__ float ldf(const float* p, long i) { return p[i]; }
__device__ __forceinline__ float ldf(const bf16* p, long i)  { return tof(p[i]); }
__device__ __forceinline__ void  stf(float* p, long i, float v) { p[i] = v; }
__device__ __forceinline__ void  stf(bf16* p, long i, float v)  { p[i] = tob(v); }
__device__ __forceinline__ void  unp(uint32 u, float& lo, float& hi) {
  lo = __uint_as_float(u << 16);
  hi = __uint_as_float(u & 0xFFFF0000u);
}
__device__ __forceinline__ uint32 pk(float lo, float hi) {
  union { bf16 h; unsigned short u; } a, b;
  a.h = tob(lo); b.h = tob(hi);
  return (uint32)a.u | ((uint32)b.u << 16);
}

// ---------------- probe: decide fp32 (flag=1) vs bf16 (flag=0) inputs ----------------
__global__ __launch_bounds__(256) void k_probe(const uint32* __restrict__ xw,
                                               int* __restrict__ flag) {
  __shared__ int s[256];
  const int tid = threadIdx.x;
  int sc = 0;
#pragma unroll
  for (int k = 0; k < 8; ++k) {
    const uint32 u = xw[tid * 8 + k];
    const float v = __uint_as_float(u << 16);  // low 16 bits as bf16
    if (!(fabsf(v) < 4.0f)) sc++;              // catches big values AND NaN/Inf
  }
  s[tid] = sc;
  __syncthreads();
  for (int o = 128; o > 0; o >>= 1) {
    if (tid < o) s[tid] += s[tid + o];
    __syncthreads();
  }
  if (tid == 0) *flag = (s[0] > 64) ? 1 : 0;
}

// ---------------- K0: fold Wk = Wr @ K^T (256x64), bk = br @ K^T (64) ----------------
template <typename T>
__device__ void k0_body(const T* Wr, const T* br, const T* K,
                        float* Wk, float* bk) {
  const int idx = blockIdx.x * 256 + threadIdx.x;
  if (idx < IN_ * M_) {
    const int i = idx >> 6, m = idx & 63;
    float acc = 0.f;
    for (int d = 0; d < D_; ++d)
      acc = fmaf(ldf(Wr, (long)i * D_ + d), ldf(K, (long)m * D_ + d), acc);
    Wk[idx] = acc;  // idx == i*M_+m
  } else if (idx < IN_ * M_ + M_) {
    const int m = idx - IN_ * M_;
    float acc = 0.f;
    for (int d = 0; d < D_; ++d)
      acc = fmaf(ldf(br, d), ldf(K, (long)m * D_ + d), acc);
    bk[m] = acc;
  }
}

__global__ __launch_bounds__(256) void k0_fold(const void* Wr, const void* br,
                                               const void* K, float* Wk, float* bk,
                                               const int* flag) {
  if (*flag) k0_body<float>((const float*)Wr, (const float*)br, (const float*)K, Wk, bk);
  else       k0_body<bf16>((const bf16*)Wr, (const bf16*)br, (const bf16*)K, Wk, bk);
}

// ---------------- K0b: pack WcatT[n][k] (192x256) and WpT[n][k] (128x128), bf16 ------
// WcatT rows 0..127 = Ww^T; rows 128..191 = (Wr@K^T)^T from fp32 Wk. flag==0 only.
__global__ __launch_bounds__(256) void k0b_pack(const void* Ww, const void* Wp,
                                                const float* Wk, bf16* WcatT,
                                                bf16* WpT, const int* flag) {
  if (*flag) return;
  const bf16* Wwb = (const bf16*)Ww;
  const bf16* Wpb = (const bf16*)Wp;
  const int idx = blockIdx.x * 256 + threadIdx.x;
  if (idx < 192 * 256) {
    const int n = idx >> 8, k = idx & 255;
    WcatT[idx] = (n < 128) ? Wwb[k * 128 + n] : tob(Wk[k * 64 + (n - 128)]);
  } else {
    const int j = idx - 192 * 256;
    const int n = j >> 7, k = j & 127;
    WpT[j] = Wpb[k * 128 + n];
  }
}

// ---------------- K1 (MFMA, flag==0): [32768x256]@[256x192] + epilogue --------------
// Block = 64 rows (4 waves x 16). a-frag: lane holds x[row=l15][k=quad*8+j];
// b-frag: lane holds WcatT[n=ct*16+l15][k=quad*8+j]; D: row=quad*4+r, col=l15.
__global__ __launch_bounds__(256) void k1_mfma(
    const bf16* __restrict__ x, const bf16* __restrict__ bw,
    const float* __restrict__ bk, const bf16* __restrict__ WcatT,
    uint32* __restrict__ ea_all, bf16* __restrict__ w_all,
    int chunk, const int* __restrict__ flag) {
  if (*flag) return;
  const int tid = threadIdx.x;
  const int wave = tid >> 6, lane = tid & 63;
  const int l15 = lane & 15, quad = lane >> 4;
  const int b = blockIdx.x >> 2, tb = blockIdx.x & 3;
  const int t0 = tb * 64 + wave * 16;
  const long lr0 = (long)b * TL_ + t0;                     // chunk-local row base
  const long ar0 = (long)b * S_ + (long)chunk * TL_ + t0;  // absolute row base

  // load 8 a-frags (K=256): 16B each, straight from global
  const bf16* xrow = x + (ar0 + l15) * IN_ + quad * 8;
  s16x8 af[8];
#pragma unroll
  for (int k = 0; k < 8; ++k) af[k] = *(const s16x8*)(xrow + k * 32);

  f32x4 acc[12];
#pragma unroll
  for (int ct = 0; ct < 12; ++ct) acc[ct] = (f32x4){0.f, 0.f, 0.f, 0.f};

#pragma unroll
  for (int ct = 0; ct < 12; ++ct) {
    const bf16* wp = WcatT + ((ct * 16 + l15) << 8) + quad * 8;
#pragma unroll
    for (int k = 0; k < 8; ++k) {
      const s16x8 bf = *(const s16x8*)(wp + k * 32);
      acc[ct] = __builtin_amdgcn_mfma_f32_16x16x32_bf16(af[k], bf, acc[ct], 0, 0, 0);
    }
  }

  // epilogue: v tiles 0..7 -> e,a packed; score tiles 8..11 -> softmax
#pragma unroll
  for (int ct = 0; ct < 8; ++ct) {
    const int col = ct * 16 + l15;
    const float bb = tof(bw[col]);
#pragma unroll
    for (int r = 0; r < 4; ++r) {
      const float v = acc[ct][r] + bb;
      const float sg = 1.0f / (1.0f + exp2f(-1.44269504f * v));
      const float th = 1.0f - 2.0f / (exp2f(2.88539008f * v) + 1.0f);
      ea_all[(lr0 + quad * 4 + r) * D_ + col] = pk(sg, th);
    }
  }
  float bks[4];
#pragma unroll
  for (int g = 0; g < 4; ++g) bks[g] = bk[g * 16 + l15];
#pragma unroll
  for (int r = 0; r < 4; ++r) {
    float s[4];
    float mx = -1e30f;
#pragma unroll
    for (int g = 0; g < 4; ++g) {
      s[g] = acc[8 + g][r] + bks[g];
      mx = fmaxf(mx, s[g]);
    }
#pragma unroll
    for (int off = 1; off < 16; off <<= 1) mx = fmaxf(mx, __shfl_xor(mx, off, 64));
    float ex[4], sum = 0.f;
#pragma unroll
    for (int g = 0; g < 4; ++g) {
      ex[g] = exp2f(1.44269504f * (s[g] - mx));
      sum += ex[g];
    }
#pragma unroll
    for (int off = 1; off < 16; off <<= 1) sum += __shfl_xor(sum, off, 64);
    const float inv = 1.0f / sum;
    const long lr = lr0 + quad * 4 + r;
#pragma unroll
    for (int g = 0; g < 4; ++g)
      w_all[lr * M_ + g * 16 + l15] = tob(ex[g] * inv);
  }
}

// ---------------- K1 (VALU fallback, flag==1): fp32 path -----------------------------
__global__ __launch_bounds__(256) void k1_valu(const void* x, const void* Ww,
                                               const void* bw, const float* Wk,
                                               const float* bk, uint32* ea_all,
                                               bf16* w_all, int chunk,
                                               const int* flag) {
  if (!*flag) return;
  __shared__ float xs[32 * 256];
  const float* xf = (const float*)x;
  const float* Wwf = (const float*)Ww;
  const float* bwf = (const float*)bw;
  const int tid = threadIdx.x;
  const int b = blockIdx.x >> 3, tb = blockIdx.x & 7;
  const long lr0 = (long)b * TL_ + tb * 32;
  const long ar0 = (long)b * S_ + (long)chunk * TL_ + tb * 32;
  const float* xg = xf + ar0 * IN_;
#pragma unroll
  for (int k = 0; k < 32; ++k) {
    const int idx = k * 256 + tid;
    xs[idx] = xg[idx];
  }
  __syncthreads();
  {
    const int c = tid & 31;
    const int rg = tid >> 5;
    float acc[4][4];
#pragma unroll
    for (int g = 0; g < 4; ++g) {
      const float bb = bwf[c + 32 * g];
#pragma unroll
      for (int r = 0; r < 4; ++r) acc[r][g] = bb;
    }
    for (int i = 0; i < IN_; i += 4) {
      float w[4][4];
#pragma unroll
      for (int k = 0; k < 4; ++k)
#pragma unroll
        for (int g = 0; g < 4; ++g)
          w[k][g] = Wwf[(long)(i + k) * D_ + c + 32 * g];
#pragma unroll
      for (int r = 0; r < 4; ++r) {
        const float4 xv = *(const float4*)&xs[(rg * 4 + r) * 256 + i];
#pragma unroll
        for (int g = 0; g < 4; ++g) {
          acc[r][g] = fmaf(xv.x, w[0][g], acc[r][g]);
          acc[r][g] = fmaf(xv.y, w[1][g], acc[r][g]);
          acc[r][g] = fmaf(xv.z, w[2][g], acc[r][g]);
          acc[r][g] = fmaf(xv.w, w[3][g], acc[r][g]);
        }
      }
    }
#pragma unroll
    for (int r = 0; r < 4; ++r) {
      const long lr = lr0 + rg * 4 + r;
#pragma unroll
      for (int g = 0; g < 4; ++g) {
        const float v = acc[r][g];
        const float sg = 1.0f / (1.0f + exp2f(-1.44269504f * v));
        const float th = 1.0f - 2.0f / (exp2f(2.88539008f * v) + 1.0f);
        ea_all[lr * D_ + c + 32 * g] = pk(sg, th);
      }
    }
  }
  {
    const int m = tid & 15;
    const int rg = tid >> 4;
    float acc[2][4];
#pragma unroll
    for (int g = 0; g < 4; ++g) {
      const float bb = bk[m + 16 * g];
#pragma unroll
      for (int r = 0; r < 2; ++r) acc[r][g] = bb;
    }
    for (int i = 0; i < IN_; i += 4) {
      float w[4][4];
#pragma unroll
      for (int k = 0; k < 4; ++k)
#pragma unroll
        for (int g = 0; g < 4; ++g)
          w[k][g] = Wk[(i + k) * M_ + m + 16 * g];
#pragma unroll
      for (int r = 0; r < 2; ++r) {
        const float4 xv = *(const float4*)&xs[(rg * 2 + r) * 256 + i];
#pragma unroll
        for (int g = 0; g < 4; ++g) {
          acc[r][g] = fmaf(xv.x, w[0][g], acc[r][g]);
          acc[r][g] = fmaf(xv.y, w[1][g], acc[r][g]);
          acc[r][g] = fmaf(xv.z, w[2][g], acc[r][g]);
          acc[r][g] = fmaf(xv.w, w[3][g], acc[r][g]);
        }
      }
    }
#pragma unroll
    for (int r = 0; r < 2; ++r) {
      float mx = fmaxf(fmaxf(acc[r][0], acc[r][1]), fmaxf(acc[r][2], acc[r][3]));
#pragma unroll
      for (int off = 8; off > 0; off >>= 1) mx = fmaxf(mx, __shfl_xor(mx, off, 64));
      float ex[4], sum = 0.f;
#pragma unroll
      for (int g = 0; g < 4; ++g) {
        ex[g] = exp2f(1.44269504f * (acc[r][g] - mx));
        sum += ex[g];
      }
#pragma unroll
      for (int off = 8; off > 0; off >>= 1) sum += __shfl_xor(sum, off, 64);
      const float inv = 1.0f / sum;
      const long lr = lr0 + rg * 2 + r;
#pragma unroll
      for (int g = 0; g < 4; ++g)
        w_all[lr * M_ + m + 16 * g] = tob(ex[g] * inv);
    }
  }
}

// ---------------- K2: scan chunk. grid = B*32 (swizzled) x 64 threads. ---------------
// blk = dg*128 + b. lane = mg*4 + dl: mg owns m = mg*4..+4; d = dg*4 + dl.
// Batch-8 register ping-pong: load bankB(t+8..15), compute bankA(t..7),
// load bankA(t+16..23), compute bankB(t+8..15).
template <typename T>
__device__ void k2_body(const T* Mv0, const uint32* ea_all, const bf16* w_all,
                        float* MvS, T* r_out, int chunk) {
  const int lane = threadIdx.x;
  const int mg = lane >> 2, dl = lane & 3;
  const int b = blockIdx.x & 127, dg = blockIdx.x >> 7;
  const int d = dg * 4 + dl;
  const int m0 = mg * 4;

  float Mv[4];
  if (chunk == 0) {
#pragma unroll
    for (int j = 0; j < 4; ++j)
      Mv[j] = ldf(Mv0, (long)(m0 + j) * D_ + d);
  } else {
#pragma unroll
    for (int j = 0; j < 4; ++j)
      Mv[j] = MvS[((long)b * M_ + m0 + j) * D_ + d];
  }

  const long lrbase = (long)b * TL_;
  const long arbase = (long)b * S_ + (long)chunk * TL_;
  const uint32* eap = ea_all + lrbase * D_ + d;
  const bf16* wap = w_all + lrbase * M_ + m0;

  uint32 erA[8], erB[8];
  uint2 wrA[8], wrB[8];
  float rbuf[8];
#pragma unroll
  for (int p = 0; p < 8; ++p) {
    erA[p] = eap[p * D_];
    wrA[p] = *(const uint2*)(wap + p * M_);
  }

  for (int t = 0; t < TL_; t += 16) {
    // load bank B = steps t+8..t+15 (always in range)
#pragma unroll
    for (int p = 0; p < 8; ++p) {
      const int ln = t + 8 + p;
      erB[p] = eap[(long)ln * D_];
      wrB[p] = *(const uint2*)(wap + (long)ln * M_);
    }
    // compute steps t..t+7 from bank A
#pragma unroll
    for (int p = 0; p < 8; ++p) {
      float e, a;
      unp(erA[p], e, a);
      float wv[4];
      unp(wrA[p].x, wv[0], wv[1]);
      unp(wrA[p].y, wv[2], wv[3]);
      float r = 0.f;
#pragma unroll
      for (int j = 0; j < 4; ++j) {
        r = fmaf(wv[j], Mv[j], r);
        Mv[j] = fmaf(wv[j], fmaf(-e, Mv[j], a), Mv[j]);
      }
      r += __shfl_xor(r, 4, 64);
      r += __shfl_xor(r, 8, 64);
      r += __shfl_xor(r, 16, 64);
      r += __shfl_xor(r, 32, 64);
      rbuf[p] = r;
    }
    if (mg == 0) {
#pragma unroll
      for (int p = 0; p < 8; ++p)
        stf(r_out, (arbase + t + p) * D_ + d, rbuf[p]);
    }
    // load bank A = steps t+16..t+23 (clamped)
#pragma unroll
    for (int p = 0; p < 8; ++p) {
      int ln = t + 16 + p;
      ln = ln < TL_ ? ln : TL_ - 1;
      erA[p] = eap[(long)ln * D_];
      wrA[p] = *(const uint2*)(wap + (long)ln * M_);
    }
    // compute steps t+8..t+15 from bank B
#pragma unroll
    for (int p = 0; p < 8; ++p) {
      float e, a;
      unp(erB[p], e, a);
      float wv[4];
      unp(wrB[p].x, wv[0], wv[1]);
      unp(wrB[p].y, wv[2], wv[3]);
      float r = 0.f;
#pragma unroll
      for (int j = 0; j < 4; ++j) {
        r = fmaf(wv[j], Mv[j], r);
        Mv[j] = fmaf(wv[j], fmaf(-e, Mv[j], a), Mv[j]);
      }
      r += __shfl_xor(r, 4, 64);
      r += __shfl_xor(r, 8, 64);
      r += __shfl_xor(r, 16, 64);
      r += __shfl_xor(r, 32, 64);
      rbuf[p] = r;
    }
    if (mg == 0) {
#pragma unroll
      for (int p = 0; p < 8; ++p)
        stf(r_out, (arbase + t + 8 + p) * D_ + d, rbuf[p]);
    }
  }
#pragma unroll
  for (int j = 0; j < 4; ++j)
    MvS[((long)b * M_ + m0 + j) * D_ + d] = Mv[j];
}

__global__ __launch_bounds__(64) void k2_scan(const void* Mv0, const uint32* ea_all,
                                              const bf16* w_all, float* MvS,
                                              void* r_out, int chunk,
                                              const int* flag) {
  if (*flag) k2_body<float>((const float*)Mv0, ea_all, w_all, MvS,
                            (float*)r_out, chunk);
  else       k2_body<bf16>((const bf16*)Mv0, ea_all, w_all, MvS,
                           (bf16*)r_out, chunk);
}

// ---------------- K3 (MFMA, flag==0): y = sigmoid(r @ Wp + bp), in place -------------
__global__ __launch_bounds__(256) void k3_mfma(const bf16* __restrict__ WpT,
                                               const bf16* __restrict__ bp,
                                               bf16* __restrict__ io,
                                               const int* __restrict__ flag) {
  if (*flag) return;
  const int tid = threadIdx.x;
  const int wave = tid >> 6, lane = tid & 63;
  const int l15 = lane & 15, quad = lane >> 4;
  const long row0 = (long)blockIdx.x * 64 + wave * 16;

  const bf16* rrow = io + (row0 + l15) * D_ + quad * 8;
  s16x8 af[4];
#pragma unroll
  for (int k = 0; k < 4; ++k) af[k] = *(const s16x8*)(rrow + k * 32);

  f32x4 acc[8];
#pragma unroll
  for (int ct = 0; ct < 8; ++ct) acc[ct] = (f32x4){0.f, 0.f, 0.f, 0.f};
#pragma unroll
  for (int ct = 0; ct < 8; ++ct) {
    const bf16* wp = WpT + ((ct * 16 + l15) << 7) + quad * 8;
#pragma unroll
    for (int k = 0; k < 4; ++k) {
      const s16x8 bf = *(const s16x8*)(wp + k * 32);
      acc[ct] = __builtin_amdgcn_mfma_f32_16x16x32_bf16(af[k], bf, acc[ct], 0, 0, 0);
    }
  }
#pragma unroll
  for (int ct = 0; ct < 8; ++ct) {
    const int col = ct * 16 + l15;
    const float bb = tof(bp[col]);
#pragma unroll
    for (int r = 0; r < 4; ++r) {
      const float y = 1.0f / (1.0f + exp2f(-1.44269504f * (acc[ct][r] + bb)));
      io[(row0 + quad * 4 + r) * OUT_ + col] = tob(y);
    }
  }
}

// ---------------- K3 (VALU fallback, flag==1) ----------------------------------------
__global__ __launch_bounds__(256) void k3_valu(const void* Wp, const void* bp,
                                               void* iov, const int* flag) {
  if (!*flag) return;
  __shared__ float rs[32 * 128];
  const float* Wpf = (const float*)Wp;
  const float* bpf = (const float*)bp;
  float* io = (float*)iov;
  const int tid = threadIdx.x;
  const long row0 = (long)blockIdx.x * 32;
#pragma unroll
  for (int k = 0; k < 16; ++k) {
    const int idx = k * 256 + tid;
    rs[idx] = io[row0 * D_ + idx];
  }
  __syncthreads();
  const int c = tid & 31;
  const int rg = tid >> 5;
  float acc[4][4];
#pragma unroll
  for (int g = 0; g < 4; ++g) {
    const float bb = bpf[c + 32 * g];
#pragma unroll
    for (int r = 0; r < 4; ++r) acc[r][g] = bb;
  }
  for (int i = 0; i < D_; i += 4) {
    float w[4][4];
#pragma unroll
    for (int k = 0; k < 4; ++k)
#pragma unroll
      for (int g = 0; g < 4; ++g)
        w[k][g] = Wpf[(long)(i + k) * OUT_ + c + 32 * g];
#pragma unroll
    for (int r = 0; r < 4; ++r) {
      const float4 xv = *(const float4*)&rs[(rg * 4 + r) * 128 + i];
#pragma unroll
      for (int g = 0; g < 4; ++g) {
        acc[r][g] = fmaf(xv.x, w[0][g], acc[r][g]);
        acc[r][g] = fmaf(xv.y, w[1][g], acc[r][g]);
        acc[r][g] = fmaf(xv.z, w[2][g], acc[r][g]);
        acc[r][g] = fmaf(xv.w, w[3][g], acc[r][g]);
      }
    }
  }
#pragma unroll
  for (int r = 0; r < 4; ++r) {
    const long row = row0 + rg * 4 + r;
#pragma unroll
    for (int g = 0; g < 4; ++g)
      io[row * OUT_ + c + 32 * g] =
          1.0f / (1.0f + exp2f(-1.44269504f * acc[r][g]));
  }
}

extern "C" void kernel_launch(void* const* d_in, const int* in_sizes, int n_in,
                              void* d_out, int out_size, void* d_ws, size_t ws_size,
                              hipStream_t stream) {
  const void* x   = d_in[0];
  const void* mk  = d_in[1];
  const void* mv  = d_in[2];
  const void* Wr  = d_in[3];
  const void* br  = d_in[4];
  const void* Ww  = d_in[5];
  const void* bwv = d_in[6];
  const void* Wp  = d_in[7];
  const void* bp  = d_in[8];

  // ws layout (~24.5 MB): flag | Wk fp32 | bk fp32 | WcatT bf16 192x256 |
  //                       WpT bf16 128x128 | ea u32 16MB | w bf16 4MB | MvS fp32 4MB
  char* ws = (char*)d_ws;
  int*    flag   = (int*)ws;
  float*  Wk     = (float*)(ws + 16);
  float*  bk     = (float*)(ws + 65552);
  bf16*   WcatT  = (bf16*)(ws + 65808);
  bf16*   WpT    = (bf16*)(ws + 65808 + 192 * 256 * 2);
  uint32* ea_all = (uint32*)(ws + 65808 + 192 * 256 * 2 + 128 * 128 * 2);
  bf16*   w_all  = (bf16*)(ea_all + (size_t)RC_ * D_);
  float*  MvS    = (float*)(w_all + (size_t)RC_ * M_);

  k_probe<<<1, 256, 0, stream>>>((const uint32*)x, flag);
  k0_fold<<<(IN_ * M_ + M_ + 255) / 256, 256, 0, stream>>>(Wr, br, mk, Wk, bk, flag);
  k0b_pack<<<256, 256, 0, stream>>>(Ww, Wp, Wk, WcatT, WpT, flag);
  for (int c = 0; c < TC_; ++c) {
    k1_mfma<<<RC_ / 64, 256, 0, stream>>>((const bf16*)x, (const bf16*)bwv, bk,
                                          WcatT, ea_all, w_all, c, flag);
    k1_valu<<<RC_ / 32, 256, 0, stream>>>(x, Ww, bwv, Wk, bk, ea_all, w_all, c, flag);
    k2_scan<<<B_ * 32, 64, 0, stream>>>(mv, ea_all, w_all, MvS, d_out, c, flag);
  }
  k3_mfma<<<(B_ * S_) / 64, 256, 0, stream>>>(WpT, (const bf16*)bp, (bf16*)d_out, flag);
  k3_valu<<<(B_ * S_) / 32, 256, 0, stream>>>(Wp, bp, d_out, flag);
}